// Round 11
// baseline (122.144 us; speedup 1.0000x reference)
//
#include <hip/hip_runtime.h>
#include <hip/hip_bf16.h>

typedef short s16x8 __attribute__((ext_vector_type(8)));
typedef unsigned u32x4 __attribute__((ext_vector_type(4)));
typedef float f32x4 __attribute__((ext_vector_type(4)));
typedef float f32x2 __attribute__((ext_vector_type(2)));

// f32 -> bf16 bits, round-to-nearest-even (prep kernel only; not hot)
static __device__ __forceinline__ short f2bf(float f) {
    unsigned u = __builtin_bit_cast(unsigned, f);
    unsigned r = (u + 0x7fffu + ((u >> 16) & 1u)) >> 16;
    return (short)r;
}

// packed f32 pair -> 2x bf16 (RNE) in one dword (v_cvt_pk_bf16_f32)
static __device__ __forceinline__ unsigned pk2bf(float a, float b) {
    __hip_bfloat162 h = __float22bfloat162_rn(make_float2(a, b));
    unsigned r;
    __builtin_memcpy(&r, &h, sizeof(r));
    return r;
}

// Pack Wcat = [W1 | W3] (512 x 128) into bf16 B-fragment order (R1 mapping):
// bws[((kk*8+nt)*64 + l)*8 + j] = Wcat[kk*32 + 8*(l>>4) + j][nt*16 + (l&15)]
__global__ void prep_weights(const float* __restrict__ W1,
                             const float* __restrict__ W3,
                             short* __restrict__ bws) {
    int tid = blockIdx.x * blockDim.x + threadIdx.x;   // 0..65535
    int j  = tid & 7;
    int l  = (tid >> 3) & 63;
    int nt = (tid >> 9) & 7;
    int kk = tid >> 12;
    int k = kk * 32 + ((l >> 4) << 3) + j;
    int n = nt * 16 + (l & 15);
    float v = (n < 64) ? W1[k * 64 + n] : W3[k * 64 + (n - 64)];
    bws[tid] = f2bf(v);
}

// R10 geometry (8 waves, 16 rows/wave, 64 KiB half-K B-tile, 2 blocks/CU).
// Single change vs R10: A-loads in ONE 16-instruction burst per K-half
// (1 KB contiguous per row-visit; each row visited exactly twice).
// Half-1's burst issues BEFORE the B-restage barrier so it flies during
// the drain + restage. No cross-burst prefetch (TLP hides; R7 falsified depth).
__global__ __launch_bounds__(512, 4)
void mf2_main(const float* __restrict__ probs, const float* __restrict__ x,
              const short* __restrict__ bws,
              const float* __restrict__ b1, const float* __restrict__ W2,
              const float* __restrict__ b2, const float* __restrict__ b3,
              const float* __restrict__ W4, const float* __restrict__ b4,
              float* __restrict__ out)
{
    __shared__ short bsh[256 * 128];   // 64 KiB: 8 kk-steps of packed [W1|W3]

    const int tid  = threadIdx.x;      // 0..511 (8 waves)
    const int lane = tid & 63;
    const int g    = lane >> 4;        // 0..3  (k-chunk group)
    const int m    = lane & 15;        // 0..15 (A-row / C-col)
    const long rowBase = (long)blockIdx.x * 128 + (tid >> 6) * 16;   // 16 rows/wave

    // A loads: lane covers k-chunks kk*32 + g*8 .. +8 of row (rowBase + m).
    // Per K-half: 16 back-to-back dwordx4 covering the row-half (1 KB) fully.
    const float* xp = x + (rowBase + m) * 512 + g * 8;

    f32x4 ra[8][2];   // raw burst buffer: one full K-half (64 VGPR)
    s16x8 af[8];      // converted bf16 fragments (32 VGPR)

    // ---- burst 0 (kk 0..7): issue BEFORE staging ----
    #pragma unroll
    for (int p = 0; p < 8; ++p) {
        const float* pp = xp + p * 32;
        ra[p][0] = *(const f32x4*)pp;
        ra[p][1] = *(const f32x4*)(pp + 4);
    }

    // ---- stage B K-half 0 (64 KiB) ----
    {
        const f32x4* src = (const f32x4*)bws;
        f32x4* dst = (f32x4*)bsh;
        #pragma unroll
        for (int it = 0; it < 8; ++it) {
            const int idx = it * 512 + tid;
            dst[idx] = src[idx];
        }
    }
    __syncthreads();

    const s16x8* bls = (const s16x8*)bsh + lane;

    f32x4 acc[8];
    #pragma unroll
    for (int nt = 0; nt < 8; ++nt)
        acc[nt] = (f32x4){0.f, 0.f, 0.f, 0.f};

    // ================= K-half 0 =================
    #pragma unroll
    for (int s = 0; s < 8; ++s) {
        u32x4 pa;
        pa[0] = pk2bf(ra[s][0][0], ra[s][0][1]);
        pa[1] = pk2bf(ra[s][0][2], ra[s][0][3]);
        pa[2] = pk2bf(ra[s][1][0], ra[s][1][1]);
        pa[3] = pk2bf(ra[s][1][2], ra[s][1][3]);
        af[s] = __builtin_bit_cast(s16x8, pa);
    }
    #pragma unroll
    for (int s = 0; s < 8; ++s)
        #pragma unroll
        for (int nt = 0; nt < 8; ++nt) {
            s16x8 b = bls[s * 512 + nt * 64];
            acc[nt] = __builtin_amdgcn_mfma_f32_16x16x32_bf16(af[s], b, acc[nt], 0, 0, 0);
        }

    // ---- burst 1 (kk 8..15): issue BEFORE the restage barrier ----
    #pragma unroll
    for (int p = 0; p < 8; ++p) {
        const float* pp = xp + 256 + p * 32;
        ra[p][0] = *(const f32x4*)pp;
        ra[p][1] = *(const f32x4*)(pp + 4);
    }

    // ---- re-stage B K-half 1 (loads above remain in flight) ----
    __syncthreads();
    {
        const f32x4* src = (const f32x4*)bws;
        f32x4* dst = (f32x4*)bsh;
        #pragma unroll
        for (int it = 0; it < 8; ++it) {
            const int idx = it * 512 + tid;
            dst[idx] = src[4096 + idx];
        }
    }
    __syncthreads();

    // ================= K-half 1 =================
    #pragma unroll
    for (int s = 0; s < 8; ++s) {
        u32x4 pa;
        pa[0] = pk2bf(ra[s][0][0], ra[s][0][1]);
        pa[1] = pk2bf(ra[s][0][2], ra[s][0][3]);
        pa[2] = pk2bf(ra[s][1][0], ra[s][1][1]);
        pa[3] = pk2bf(ra[s][1][2], ra[s][1][3]);
        af[s] = __builtin_bit_cast(s16x8, pa);
    }
    #pragma unroll
    for (int s = 0; s < 8; ++s)
        #pragma unroll
        for (int nt = 0; nt < 8; ++nt) {
            s16x8 b = bls[s * 512 + nt * 64];
            acc[nt] = __builtin_amdgcn_mfma_f32_16x16x32_bf16(af[s], b, acc[nt], 0, 0, 0);
        }

    // ---- epilogue (weight/bias loads deferred past the loop) ----
    float w2r[4][4];
    float w4r[4][2];
    float biasr[8];
    #pragma unroll
    for (int nt = 0; nt < 4; ++nt) {
        const int col = m + 16 * nt;
        f32x4 w2v = *(const f32x4*)(W2 + col * 4);
        #pragma unroll
        for (int c = 0; c < 4; ++c) w2r[nt][c] = w2v[c];
        f32x2 w4v = *(const f32x2*)(W4 + col * 2);
        w4r[nt][0] = w4v[0]; w4r[nt][1] = w4v[1];
    }
    #pragma unroll
    for (int nt = 0; nt < 8; ++nt) {
        const int col = m + 16 * nt;
        biasr[nt] = (col < 64) ? b1[col] : b3[col - 64];
    }
    float b2v[4], b4v[2];
    #pragma unroll
    for (int c = 0; c < 4; ++c) b2v[c] = b2[c];
    #pragma unroll
    for (int c = 0; c < 2; ++c) b4v[c] = b4[c];

    // bias+relu, layer-2 partials, 16-lane butterfly reduce.
    // C layout: lane holds row 4*g + r, col m + 16*nt (reg r).
    float own[6] = {0.f, 0.f, 0.f, 0.f, 0.f, 0.f};
    #pragma unroll
    for (int r = 0; r < 4; ++r) {
        float v[6] = {0.f, 0.f, 0.f, 0.f, 0.f, 0.f};
        #pragma unroll
        for (int nt = 0; nt < 4; ++nt) {
            float h = fmaxf(acc[nt][r] + biasr[nt], 0.f);
            v[0] += h * w2r[nt][0];
            v[1] += h * w2r[nt][1];
            v[2] += h * w2r[nt][2];
            v[3] += h * w2r[nt][3];
        }
        #pragma unroll
        for (int j = 0; j < 4; ++j) {
            float h = fmaxf(acc[4 + j][r] + biasr[4 + j], 0.f);
            v[4] += h * w4r[j][0];
            v[5] += h * w4r[j][1];
        }
        #pragma unroll
        for (int msk = 1; msk <= 8; msk <<= 1) {
            #pragma unroll
            for (int c = 0; c < 6; ++c) v[c] += __shfl_xor(v[c], msk, 64);
        }
        if (m == r) {
            #pragma unroll
            for (int c = 0; c < 6; ++c) own[c] = v[c];
        }
    }

    // lanes m<4 finish one row each: sigmoid head + 2-class softmax
    if (m < 4) {
        const long row = rowBase + g * 4 + m;
        f32x4 pr = *(const f32x4*)(probs + row * 4);   // p00 p01 p10 p11
        float mu1[2], mu2[2], icv[2];
        #pragma unroll
        for (int c = 0; c < 2; ++c) {
            mu1[c] = 1.0f / (1.0f + __expf(-(own[c]     + b2v[c])));
            mu2[c] = 1.0f / (1.0f + __expf(-(own[2 + c] + b2v[2 + c])));
            icv[c] = 1.0f / (1.0f + __expf(-(own[4 + c] + b4v[c])));
        }
        float res[2];
        #pragma unroll
        for (int c = 0; c < 2; ++c) {
            float p0 = pr[c], p1 = pr[2 + c];
            float m12 = fminf(fmaxf(mu1[c], mu2[c]) + icv[c], 1.0f);
            res[c] = (p0 <= p1) ? (p0 * mu1[c] + (p1 - p0) * m12)
                                : (p1 * mu2[c] + (p0 - p1) * m12);
        }
        float d01 = res[0] - res[1];
        f32x2 o;
        o[0] = 1.0f / (1.0f + __expf(-d01));
        o[1] = 1.0f / (1.0f + __expf(d01));
        *(f32x2*)(out + row * 2) = o;
    }
}

extern "C" void kernel_launch(void* const* d_in, const int* in_sizes, int n_in,
                              void* d_out, int out_size, void* d_ws, size_t ws_size,
                              hipStream_t stream)
{
    const float* probs = (const float*)d_in[0];
    const float* x     = (const float*)d_in[1];
    const float* W1    = (const float*)d_in[2];
    const float* b1    = (const float*)d_in[3];
    const float* W2    = (const float*)d_in[4];
    const float* b2    = (const float*)d_in[5];
    const float* W3    = (const float*)d_in[6];
    const float* b3    = (const float*)d_in[7];
    const float* W4    = (const float*)d_in[8];
    const float* b4    = (const float*)d_in[9];
    float* out = (float*)d_out;
    short* bws = (short*)d_ws;   // 512*128 bf16 = 128 KiB

    hipLaunchKernelGGL(prep_weights, dim3(256), dim3(256), 0, stream, W1, W3, bws);
    hipLaunchKernelGGL(mf2_main, dim3(2048), dim3(512), 0, stream,
                       probs, x, bws, b1, W2, b2, b3, W4, b4, out);
}